// Round 1
// baseline (766.633 us; speedup 1.0000x reference)
//
#include <hip/hip_runtime.h>

#define D 64
#define NPB 16  // nodes per block in the GEMM kernel

// Phase 1: agg[dst[e]] += x[src[e]]  -- 16 threads per edge, float4 per thread.
__global__ void scatter_add_kernel(const float* __restrict__ x,
                                   const int* __restrict__ src,
                                   const int* __restrict__ dst,
                                   float* __restrict__ agg,
                                   int n_edges) {
    int gid = blockIdx.x * blockDim.x + threadIdx.x;
    int e = gid >> 4;
    if (e >= n_edges) return;
    int c = (gid & 15) << 2;  // feature offset 0,4,...,60
    int s = src[e];
    int d = dst[e];
    const float4 v = *reinterpret_cast<const float4*>(x + (size_t)s * D + c);
    float* a = agg + (size_t)d * D + c;
    unsafeAtomicAdd(a + 0, v.x);
    unsafeAtomicAdd(a + 1, v.y);
    unsafeAtomicAdd(a + 2, v.z);
    unsafeAtomicAdd(a + 3, v.w);
}

// Phase 2: out[n][o] = relu(sum_d agg[n][d] * W[o][d]) + x[n][o]
// 256 threads = 4 groups of 64; each group handles one node per iteration.
__global__ void linear_relu_res_kernel(const float* __restrict__ agg,
                                       const float* __restrict__ W,
                                       const float* __restrict__ x,
                                       float* __restrict__ out,
                                       int n_nodes) {
    __shared__ float Ws[D][68];   // +4 pad: keeps float4 alignment, breaks pow2 stride
    __shared__ float As[4][D];

    for (int i = threadIdx.x; i < D * D; i += 256) {
        Ws[i >> 6][i & 63] = W[i];
    }

    const int g = threadIdx.x >> 6;   // node group 0..3
    const int o = threadIdx.x & 63;   // output feature
    const int base = blockIdx.x * NPB;

    for (int it = 0; it < NPB / 4; ++it) {
        const int n = base + it * 4 + g;
        __syncthreads();  // Ws visible (iter 0); As consumed (iters >0)
        if (n < n_nodes) As[g][o] = agg[(size_t)n * D + o];
        __syncthreads();
        if (n < n_nodes) {
            float acc = 0.0f;
#pragma unroll
            for (int k = 0; k < D / 4; ++k) {
                const float4 wv = *reinterpret_cast<const float4*>(&Ws[o][k * 4]);
                const float4 av = *reinterpret_cast<const float4*>(&As[g][k * 4]);
                acc = fmaf(wv.x, av.x, acc);
                acc = fmaf(wv.y, av.y, acc);
                acc = fmaf(wv.z, av.z, acc);
                acc = fmaf(wv.w, av.w, acc);
            }
            out[(size_t)n * D + o] = fmaxf(acc, 0.0f) + x[(size_t)n * D + o];
        }
    }
}

extern "C" void kernel_launch(void* const* d_in, const int* in_sizes, int n_in,
                              void* d_out, int out_size, void* d_ws, size_t ws_size,
                              hipStream_t stream) {
    const float* x = (const float*)d_in[0];
    const float* W = (const float*)d_in[1];
    const int* src = (const int*)d_in[2];
    const int* dst = (const int*)d_in[3];
    float* out = (float*)d_out;

    const int n_nodes = in_sizes[0] / D;
    const int n_edges = in_sizes[2];

    float* agg = (float*)d_ws;  // n_nodes * D floats

    hipMemsetAsync(agg, 0, (size_t)n_nodes * D * sizeof(float), stream);

    {
        const int threads = n_edges * 16;
        const int block = 256;
        const int grid = (threads + block - 1) / block;
        scatter_add_kernel<<<grid, block, 0, stream>>>(x, src, dst, agg, n_edges);
    }
    {
        const int grid = (n_nodes + NPB - 1) / NPB;
        linear_relu_res_kernel<<<grid, 256, 0, stream>>>(agg, W, x, out, n_nodes);
    }
}

// Round 2
// 198.364 us; speedup vs baseline: 3.8648x; 3.8648x over previous
//
#include <hip/hip_runtime.h>

#define D 64
#define WPAD 68  // W row stride in LDS: 68 floats -> float4 reads hit min bank aliasing

// ---------- CSR build ----------

__global__ void hist_kernel(const int* __restrict__ dst, int* __restrict__ counts, int ne) {
    int e = blockIdx.x * blockDim.x + threadIdx.x;
    if (e < ne) atomicAdd(&counts[dst[e]], 1);
}

// Block-level exclusive scan (Hillis-Steele over 256 elems)
__global__ void scan1_kernel(const int* __restrict__ counts, int* __restrict__ scanned,
                             int* __restrict__ bsums, int n) {
    __shared__ int s[256];
    const int t = threadIdx.x;
    const int i = blockIdx.x * 256 + t;
    const int v = (i < n) ? counts[i] : 0;
    s[t] = v;
    __syncthreads();
    for (int off = 1; off < 256; off <<= 1) {
        int u = (t >= off) ? s[t - off] : 0;
        __syncthreads();
        s[t] += u;
        __syncthreads();
    }
    if (i < n) scanned[i] = s[t] - v;  // exclusive
    if (t == 255) bsums[blockIdx.x] = s[255];
}

__global__ void scan2_kernel(const int* __restrict__ bsums, int* __restrict__ bscan, int nb) {
    __shared__ int s[256];
    const int t = threadIdx.x;
    const int v = (t < nb) ? bsums[t] : 0;
    s[t] = v;
    __syncthreads();
    for (int off = 1; off < 256; off <<= 1) {
        int u = (t >= off) ? s[t - off] : 0;
        __syncthreads();
        s[t] += u;
        __syncthreads();
    }
    if (t < nb) bscan[t] = s[t] - v;  // exclusive
}

__global__ void scan3_kernel(const int* __restrict__ scanned, const int* __restrict__ bscan,
                             int* __restrict__ offsets, int n) {
    int i = blockIdx.x * 256 + threadIdx.x;
    if (i < n) offsets[i] = scanned[i] + bscan[blockIdx.x];
}

__global__ void fill_kernel(const int* __restrict__ src, const int* __restrict__ dst,
                            const int* __restrict__ offsets, int* __restrict__ cursor,
                            int* __restrict__ esrc, int ne) {
    int e = blockIdx.x * blockDim.x + threadIdx.x;
    if (e < ne) {
        int d = dst[e];
        int p = atomicAdd(&cursor[d], 1);
        esrc[offsets[d] + p] = src[e];
    }
}

// ---------- fused gather-sum + linear + relu + residual ----------
// One wave per node (lane = feature). agg row -> LDS transpose -> 64x64 dot vs W in LDS.
__global__ void gather_linear_kernel(const int* __restrict__ offsets, const int* __restrict__ counts,
                                     const int* __restrict__ esrc, const float* __restrict__ x,
                                     const float* __restrict__ W, float* __restrict__ out,
                                     int n_nodes) {
    __shared__ float Ws[D * WPAD];
    __shared__ float As[4][D];

    for (int i = threadIdx.x; i < D * D; i += 256) {
        Ws[(i >> 6) * WPAD + (i & 63)] = W[i];
    }
    __syncthreads();

    const int w = threadIdx.x >> 6;
    const int lane = threadIdx.x & 63;
    const int waveId = blockIdx.x * 4 + w;
    const int nWaves = gridDim.x * 4;
    const int iters = (n_nodes + nWaves - 1) / nWaves;  // uniform across block

    for (int it = 0; it < iters; ++it) {
        const int n = waveId + it * nWaves;
        const bool act = (n < n_nodes);
        float acc = 0.0f;
        if (act) {
            const int start = offsets[n];
            const int c = counts[n];
            int j = 0;
            for (; j + 4 <= c; j += 4) {
                const int s0 = esrc[start + j + 0];
                const int s1 = esrc[start + j + 1];
                const int s2 = esrc[start + j + 2];
                const int s3 = esrc[start + j + 3];
                const float v0 = x[(size_t)s0 * D + lane];
                const float v1 = x[(size_t)s1 * D + lane];
                const float v2 = x[(size_t)s2 * D + lane];
                const float v3 = x[(size_t)s3 * D + lane];
                acc += v0;
                acc += v1;
                acc += v2;
                acc += v3;
            }
            for (; j < c; ++j) acc += x[(size_t)esrc[start + j] * D + lane];
        }
        __syncthreads();
        if (act) As[w][lane] = acc;
        __syncthreads();
        if (act) {
            float h = 0.0f;
#pragma unroll
            for (int k = 0; k < D / 4; ++k) {
                const float4 av = *reinterpret_cast<const float4*>(&As[w][k * 4]);
                const float4 wv = *reinterpret_cast<const float4*>(&Ws[lane * WPAD + k * 4]);
                h = fmaf(av.x, wv.x, h);
                h = fmaf(av.y, wv.y, h);
                h = fmaf(av.z, wv.z, h);
                h = fmaf(av.w, wv.w, h);
            }
            out[(size_t)n * D + lane] = fmaxf(h, 0.0f) + x[(size_t)n * D + lane];
        }
    }
}

extern "C" void kernel_launch(void* const* d_in, const int* in_sizes, int n_in,
                              void* d_out, int out_size, void* d_ws, size_t ws_size,
                              hipStream_t stream) {
    const float* x = (const float*)d_in[0];
    const float* W = (const float*)d_in[1];
    const int* src = (const int*)d_in[2];
    const int* dst = (const int*)d_in[3];
    float* out = (float*)d_out;

    const int n_nodes = in_sizes[0] / D;
    const int n_edges = in_sizes[2];

    // workspace layout (ints)
    int* counts  = (int*)d_ws;              // n_nodes
    int* cursor  = counts + n_nodes;        // n_nodes  (zeroed with counts)
    int* scanned = cursor + n_nodes;        // n_nodes
    int* offsets = scanned + n_nodes;       // n_nodes
    int* bsums   = offsets + n_nodes;       // 256
    int* bscan   = bsums + 256;             // 256
    int* esrc    = bscan + 256;             // n_edges

    hipMemsetAsync(counts, 0, (size_t)2 * n_nodes * sizeof(int), stream);

    const int egrid = (n_edges + 255) / 256;
    const int ngrid = (n_nodes + 255) / 256;  // 196 <= 256, fits scan2

    hist_kernel<<<egrid, 256, 0, stream>>>(dst, counts, n_edges);
    scan1_kernel<<<ngrid, 256, 0, stream>>>(counts, scanned, bsums, n_nodes);
    scan2_kernel<<<1, 256, 0, stream>>>(bsums, bscan, ngrid);
    scan3_kernel<<<ngrid, 256, 0, stream>>>(scanned, bscan, offsets, n_nodes);
    fill_kernel<<<egrid, 256, 0, stream>>>(src, dst, offsets, cursor, esrc, n_edges);

    gather_linear_kernel<<<2048, 256, 0, stream>>>(offsets, counts, esrc, x, W, out, n_nodes);
}

// Round 3
// 163.180 us; speedup vs baseline: 4.6981x; 1.2156x over previous
//
#include <hip/hip_runtime.h>

#define D 64
#define WPAD 68   // W row stride in LDS
#define CPAD 16   // counts stride in ints: one counter per 64B L2 line

// rank[e] = arrival order of edge e among edges sharing dst; counts[d*CPAD] = degree
__global__ void rank_hist_kernel(const int* __restrict__ dst, int* __restrict__ counts,
                                 int* __restrict__ rank, int ne) {
    int e = blockIdx.x * blockDim.x + threadIdx.x;
    if (e < ne) {
        int d = dst[e];
        rank[e] = atomicAdd(&counts[(size_t)d * CPAD], 1);
    }
}

// Exclusive scan of padded counts, 256/block
__global__ void scan1_kernel(const int* __restrict__ counts, int* __restrict__ scanned,
                             int* __restrict__ bsums, int n) {
    __shared__ int s[256];
    const int t = threadIdx.x;
    const int i = blockIdx.x * 256 + t;
    const int v = (i < n) ? counts[(size_t)i * CPAD] : 0;
    s[t] = v;
    __syncthreads();
    for (int off = 1; off < 256; off <<= 1) {
        int u = (t >= off) ? s[t - off] : 0;
        __syncthreads();
        s[t] += u;
        __syncthreads();
    }
    if (i < n) scanned[i] = s[t] - v;  // exclusive within block
    if (t == 255) bsums[blockIdx.x] = s[255];
}

__global__ void scan2_kernel(const int* __restrict__ bsums, int* __restrict__ bscan, int nb) {
    __shared__ int s[256];
    const int t = threadIdx.x;
    const int v = (t < nb) ? bsums[t] : 0;
    s[t] = v;
    __syncthreads();
    for (int off = 1; off < 256; off <<= 1) {
        int u = (t >= off) ? s[t - off] : 0;
        __syncthreads();
        s[t] += u;
        __syncthreads();
    }
    if (t < nb) bscan[t] = s[t] - v;  // exclusive
}

// Atomic-free placement using precomputed ranks
__global__ void place_kernel(const int* __restrict__ src, const int* __restrict__ dst,
                             const int* __restrict__ scanned, const int* __restrict__ bscan,
                             const int* __restrict__ rank, int* __restrict__ esrc, int ne) {
    int e = blockIdx.x * blockDim.x + threadIdx.x;
    if (e < ne) {
        int d = dst[e];
        esrc[scanned[d] + bscan[d >> 8] + rank[e]] = src[e];
    }
}

// Fused gather-sum + linear + relu + residual. One wave per node, lane = feature.
__global__ void gather_linear_kernel(const int* __restrict__ scanned, const int* __restrict__ bscan,
                                     const int* __restrict__ counts,
                                     const int* __restrict__ esrc, const float* __restrict__ x,
                                     const float* __restrict__ W, float* __restrict__ out,
                                     int n_nodes) {
    __shared__ float Ws[D * WPAD];
    __shared__ float As[4][D];

    for (int i = threadIdx.x; i < D * D; i += 256) {
        Ws[(i >> 6) * WPAD + (i & 63)] = W[i];
    }
    __syncthreads();

    const int w = threadIdx.x >> 6;
    const int lane = threadIdx.x & 63;
    const int waveId = blockIdx.x * 4 + w;
    const int nWaves = gridDim.x * 4;
    const int iters = (n_nodes + nWaves - 1) / nWaves;  // uniform across block

    for (int it = 0; it < iters; ++it) {
        const int n = waveId + it * nWaves;
        const bool act = (n < n_nodes);
        float acc = 0.0f;
        if (act) {
            const int start = scanned[n] + bscan[n >> 8];
            const int c = counts[(size_t)n * CPAD];
            int j = 0;
            for (; j + 4 <= c; j += 4) {
                const int s0 = esrc[start + j + 0];
                const int s1 = esrc[start + j + 1];
                const int s2 = esrc[start + j + 2];
                const int s3 = esrc[start + j + 3];
                acc += x[(size_t)s0 * D + lane];
                acc += x[(size_t)s1 * D + lane];
                acc += x[(size_t)s2 * D + lane];
                acc += x[(size_t)s3 * D + lane];
            }
            for (; j < c; ++j) acc += x[(size_t)esrc[start + j] * D + lane];
        }
        __syncthreads();
        if (act) As[w][lane] = acc;
        __syncthreads();
        if (act) {
            float h = 0.0f;
#pragma unroll
            for (int k = 0; k < D / 4; ++k) {
                const float4 av = *reinterpret_cast<const float4*>(&As[w][k * 4]);
                const float4 wv = *reinterpret_cast<const float4*>(&Ws[lane * WPAD + k * 4]);
                h = fmaf(av.x, wv.x, h);
                h = fmaf(av.y, wv.y, h);
                h = fmaf(av.z, wv.z, h);
                h = fmaf(av.w, wv.w, h);
            }
            out[(size_t)n * D + lane] = fmaxf(h, 0.0f) + x[(size_t)n * D + lane];
        }
    }
}

extern "C" void kernel_launch(void* const* d_in, const int* in_sizes, int n_in,
                              void* d_out, int out_size, void* d_ws, size_t ws_size,
                              hipStream_t stream) {
    const float* x = (const float*)d_in[0];
    const float* W = (const float*)d_in[1];
    const int* src = (const int*)d_in[2];
    const int* dst = (const int*)d_in[3];
    float* out = (float*)d_out;

    const int n_nodes = in_sizes[0] / D;
    const int n_edges = in_sizes[2];

    // workspace layout (ints): total ~9.8 MB (< the 12.8 MB proven available in R1)
    int* counts  = (int*)d_ws;                    // n_nodes * CPAD (padded)
    int* scanned = counts + (size_t)n_nodes * CPAD;  // n_nodes
    int* bsums   = scanned + n_nodes;             // 256
    int* bscan   = bsums + 256;                   // 256
    int* rank    = bscan + 256;                   // n_edges
    int* esrc    = rank + n_edges;                // n_edges

    hipMemsetAsync(counts, 0, (size_t)n_nodes * CPAD * sizeof(int), stream);

    const int egrid = (n_edges + 255) / 256;
    const int ngrid = (n_nodes + 255) / 256;  // 196 <= 256, fits scan2 in one block

    rank_hist_kernel<<<egrid, 256, 0, stream>>>(dst, counts, rank, n_edges);
    scan1_kernel<<<ngrid, 256, 0, stream>>>(counts, scanned, bsums, n_nodes);
    scan2_kernel<<<1, 256, 0, stream>>>(bsums, bscan, ngrid);
    place_kernel<<<egrid, 256, 0, stream>>>(src, dst, scanned, bscan, rank, esrc, n_edges);

    gather_linear_kernel<<<2048, 256, 0, stream>>>(scanned, bscan, counts, esrc, x, W, out, n_nodes);
}